// Round 8
// baseline (171.198 us; speedup 1.0000x reference)
//
#include <hip/hip_runtime.h>

#define KTOP 100
#define NCOL 16384
#define TPB  1024
#define NCHUNK (NCOL / (TPB * 4))   // 4 float4 (16 values) per thread, in registers
#define HW0  1032                   // packed fallback: per-copy stride, 1024 words (2048 bins) + 8 pad
#define HST  520                    // common path: per-copy stride, 512 words + 8 pad
#define CAP  1024                   // candidate list capacity
#define BIN0 1536u                  // bin index of enc(+2.0f) >> 21
#define FT0  2.0f                   // histogram threshold; enc(2.0f)=0xC0000000 aligns to bin 1536

// order-preserving key transform: a<b (float) <=> enc(a)<enc(b) (uint)
__device__ __forceinline__ unsigned enc(unsigned u) {
    return u ^ (((unsigned)((int)u >> 31)) | 0x80000000u);
}
__device__ __forceinline__ unsigned dec(unsigned k) {
    return k ^ ((k & 0x80000000u) ? 0x80000000u : 0xFFFFFFFFu);
}
__device__ __forceinline__ unsigned encf(float f) { return enc(__float_as_uint(f)); }

// packed-16 boundary scan over 2048 bins (fallback path), 2 copies at stride HW0
__device__ __forceinline__ void boundary_scan_packed(const unsigned* hist, int lane, unsigned kcur,
                                                     unsigned& obin, unsigned& ok, unsigned& oeq) {
    unsigned own = 0;
    #pragma unroll
    for (int w = 0; w < 16; ++w) {
        unsigned s = hist[16 * lane + w] + hist[HW0 + 16 * lane + w];
        own += (s & 0xFFFFu) + (s >> 16);
    }
    unsigned incl = own;
    #pragma unroll
    for (int s = 1; s < 64; s <<= 1) {
        unsigned v = __shfl_down(incl, s);
        if (lane + s < 64) incl += v;
    }
    unsigned above = incl - own;
    bool hit = (above < kcur) && (above + own >= kcur);
    unsigned long long bal = __ballot(hit);
    int L = __ffsll((long long)bal) - 1;
    unsigned run = __shfl(above, L);
    unsigned sbin = 0, sk = 1, seq = 1;
    for (int w = 15; w >= 0; --w) {
        unsigned s = hist[16 * L + w] + hist[HW0 + 16 * L + w];
        unsigned chi = s >> 16, clo = s & 0xFFFFu;
        unsigned r1 = run + chi;
        if (run < kcur && r1 >= kcur) { sbin = 32u * L + 2u * w + 1u; sk = kcur - run; seq = chi; }
        unsigned r2 = r1 + clo;
        if (r1 < kcur && r2 >= kcur) { sbin = 32u * L + 2u * w;       sk = kcur - r1;  seq = clo; }
        run = r2;
    }
    obin = sbin; ok = sk; oeq = seq;
}

__global__ __launch_bounds__(TPB, 8)
void topk_act_kernel(const float* __restrict__ x, float* __restrict__ out) {
    __shared__ unsigned hist[2 * HW0];       // 8.25 KB (fallback 2*HW0; common 2*HST; tie path reuses)
    __shared__ unsigned cand[CAP];           // 4 KB
    __shared__ unsigned s_cnt, s_pos;

    const int row  = blockIdx.x;
    const int tid  = threadIdx.x;
    const int lane = tid & 63;
    const int wv   = tid >> 6;

    const float4* __restrict__ xrow = (const float4*)(x + (size_t)row * NCOL);
    float4* __restrict__ orow = (float4*)(out + (size_t)row * NCOL);

    for (int i = tid; i < 2 * HST; i += TPB) hist[i] = 0;
    if (tid == 0) { s_cnt = 0; s_pos = 0; }
    __syncthreads();

    // ---- load -> registers; all-below-2.0 groups store zero IMMEDIATELY (overlaps writes
    //      with reads + selection); >=2.0 elements (~373/row) histogrammed into 512 bins ----
    unsigned* myh = hist + (wv & 1) * HST;
    float4 v[NCHUNK];
    unsigned defer = 0, pcnt = 0;
    #pragma unroll
    for (int j = 0; j < NCHUNK; ++j) {
        v[j] = xrow[tid + j * TPB];
        bool b0 = v[j].x >= FT0, b1 = v[j].y >= FT0, b2 = v[j].z >= FT0, b3 = v[j].w >= FT0;
        if (b0 | b1 | b2 | b3) {
            defer |= 1u << j;
            if (b0) { atomicAdd(&myh[(encf(v[j].x) >> 21) - BIN0], 1u); ++pcnt; }
            if (b1) { atomicAdd(&myh[(encf(v[j].y) >> 21) - BIN0], 1u); ++pcnt; }
            if (b2) { atomicAdd(&myh[(encf(v[j].z) >> 21) - BIN0], 1u); ++pcnt; }
            if (b3) { atomicAdd(&myh[(encf(v[j].w) >> 21) - BIN0], 1u); ++pcnt; }
        } else {
            orow[tid + j * TPB] = make_float4(0.f, 0.f, 0.f, 0.f);   // optimistic zero
        }
    }
    #pragma unroll
    for (int s = 1; s < 64; s <<= 1) pcnt += __shfl_down(pcnt, s);
    if (lane == 0) atomicAdd(&s_pos, pcnt);
    __syncthreads();

    unsigned pref, kcur, eqc;
    const bool common = (s_pos >= KTOP);    // uniform across block
    if (common) {
        // ---- boundary scan over 512 unpacked bins; lane owns 8 ----
        unsigned own = 0;
        #pragma unroll
        for (int w = 0; w < 8; ++w) own += hist[8 * lane + w] + hist[HST + 8 * lane + w];
        unsigned incl = own;
        #pragma unroll
        for (int s = 1; s < 64; s <<= 1) {
            unsigned t = __shfl_down(incl, s);
            if (lane + s < 64) incl += t;
        }
        unsigned above = incl - own;
        bool hit = (above < KTOP) && (above + own >= KTOP);
        unsigned long long bal = __ballot(hit);
        int L = __ffsll((long long)bal) - 1;
        unsigned run = __shfl(above, L);
        unsigned sbin = 0, sk = 1, seq = 1;
        for (int w = 7; w >= 0; --w) {
            unsigned c = hist[8 * L + w] + hist[HST + 8 * L + w];
            unsigned r = run + c;
            if (run < KTOP && r >= KTOP) { sbin = 8u * L + (unsigned)w; sk = KTOP - run; seq = c; }
            run = r;
        }
        pref = (sbin + BIN0) << 21; kcur = sk; eqc = seq;
    } else {
        // ---- rare fallback (optimistic zeros will be overwritten below): full 2048-bin packed ----
        for (int i = tid; i < 2 * HW0; i += TPB) hist[i] = 0;
        __syncthreads();
        unsigned* mh = hist + (wv & 1) * HW0;
        #pragma unroll
        for (int j = 0; j < NCHUNK; ++j) {
            unsigned k0 = encf(v[j].x), k1 = encf(v[j].y), k2 = encf(v[j].z), k3 = encf(v[j].w);
            atomicAdd(&mh[k0 >> 22], 1u << (((k0 >> 21) & 1u) << 4));
            atomicAdd(&mh[k1 >> 22], 1u << (((k1 >> 21) & 1u) << 4));
            atomicAdd(&mh[k2 >> 22], 1u << (((k2 >> 21) & 1u) << 4));
            atomicAdd(&mh[k3 >> 22], 1u << (((k3 >> 21) & 1u) << 4));
        }
        __syncthreads();
        unsigned b, kk, e;
        boundary_scan_packed(hist, lane, KTOP, b, kk, e);
        pref = b << 21; kcur = kk; eqc = e;
    }

    bool done = (kcur == eqc);   // keep whole boundary bin: T = bin floor

    if (!done) {
        // ---- extract boundary-bin candidates into LDS list ----
        const unsigned bin0 = pref >> 21;
        if (common) {
            // only deferred groups can contain bin >= BIN0 elements
            #pragma unroll
            for (int j = 0; j < NCHUNK; ++j) if ((defer >> j) & 1u) {
                unsigned k0 = encf(v[j].x), k1 = encf(v[j].y), k2 = encf(v[j].z), k3 = encf(v[j].w);
                if ((k0 >> 21) == bin0) { unsigned i = atomicAdd(&s_cnt, 1u); if (i < CAP) cand[i] = k0; }
                if ((k1 >> 21) == bin0) { unsigned i = atomicAdd(&s_cnt, 1u); if (i < CAP) cand[i] = k1; }
                if ((k2 >> 21) == bin0) { unsigned i = atomicAdd(&s_cnt, 1u); if (i < CAP) cand[i] = k2; }
                if ((k3 >> 21) == bin0) { unsigned i = atomicAdd(&s_cnt, 1u); if (i < CAP) cand[i] = k3; }
            }
        } else {
            #pragma unroll
            for (int j = 0; j < NCHUNK; ++j) {
                unsigned k0 = encf(v[j].x), k1 = encf(v[j].y), k2 = encf(v[j].z), k3 = encf(v[j].w);
                if ((k0 >> 21) == bin0) { unsigned i = atomicAdd(&s_cnt, 1u); if (i < CAP) cand[i] = k0; }
                if ((k1 >> 21) == bin0) { unsigned i = atomicAdd(&s_cnt, 1u); if (i < CAP) cand[i] = k1; }
                if ((k2 >> 21) == bin0) { unsigned i = atomicAdd(&s_cnt, 1u); if (i < CAP) cand[i] = k2; }
                if ((k3 >> 21) == bin0) { unsigned i = atomicAdd(&s_cnt, 1u); if (i < CAP) cand[i] = k3; }
            }
        }
        __syncthreads();
        const unsigned mtot = s_cnt;
        const bool use_list = (mtot <= CAP);

        // ---- passes 1-3: 7 bits each over candidate list (register fallback if overflow) ----
        for (int p = 1; p <= 3 && !done; ++p) {
            const int shift = 21 - 7 * p;        // 14, 7, 0
            __syncthreads();
            for (int i = tid; i < 128; i += TPB) hist[i] = 0;
            __syncthreads();
            if (use_list) {
                for (unsigned i = tid; i < mtot; i += TPB) {
                    unsigned k = cand[i];
                    if (((k ^ pref) >> (shift + 7)) == 0)
                        atomicAdd(&hist[(k >> shift) & 0x7Fu], 1u);
                }
            } else {
                #pragma unroll
                for (int j = 0; j < NCHUNK; ++j) if (!common || ((defer >> j) & 1u)) {
                    unsigned k0 = encf(v[j].x), k1 = encf(v[j].y), k2 = encf(v[j].z), k3 = encf(v[j].w);
                    if (((k0 ^ pref) >> (shift + 7)) == 0) atomicAdd(&hist[(k0 >> shift) & 0x7Fu], 1u);
                    if (((k1 ^ pref) >> (shift + 7)) == 0) atomicAdd(&hist[(k1 >> shift) & 0x7Fu], 1u);
                    if (((k2 ^ pref) >> (shift + 7)) == 0) atomicAdd(&hist[(k2 >> shift) & 0x7Fu], 1u);
                    if (((k3 ^ pref) >> (shift + 7)) == 0) atomicAdd(&hist[(k3 >> shift) & 0x7Fu], 1u);
                }
            }
            __syncthreads();
            unsigned t0 = hist[2 * lane], t1 = hist[2 * lane + 1];
            unsigned own = t0 + t1, incl = own;
            #pragma unroll
            for (int s = 1; s < 64; s <<= 1) {
                unsigned t = __shfl_down(incl, s);
                if (lane + s < 64) incl += t;
            }
            unsigned above = incl - own;
            unsigned C1 = above + t1;
            unsigned C0 = C1 + t0;
            bool h1 = (above < kcur) && (C1 >= kcur);
            bool h0 = (C1 < kcur) && (C0 >= kcur);
            unsigned mybin = h1 ? (2u * lane + 1u) : (2u * lane);
            unsigned myk   = h1 ? (kcur - above) : (kcur - C1);
            unsigned myeq  = h1 ? t1 : t0;
            unsigned long long bal = __ballot(h0 || h1);
            int L = __ffsll((long long)bal) - 1;
            pref |= __shfl(mybin, L) << shift;
            kcur  = __shfl(myk, L);
            eqc   = __shfl(myeq, L);
            if (kcur == eqc) done = true;
        }
    }

    const unsigned T = pref;
    const unsigned krem = kcur;

    if (done || krem == eqc) {
        if (common) {
            // ---- fast path: only deferred groups left; plain float compare (T >= 2.0 > 0) ----
            const float fT = __uint_as_float(dec(T));
            #pragma unroll
            for (int j = 0; j < NCHUNK; ++j) if ((defer >> j) & 1u) {
                float4 o;
                o.x = (v[j].x >= fT) ? v[j].x : 0.f;
                o.y = (v[j].y >= fT) ? v[j].y : 0.f;
                o.z = (v[j].z >= fT) ? v[j].z : 0.f;
                o.w = (v[j].w >= fT) ? v[j].w : 0.f;
                orow[tid + j * TPB] = o;
            }
        } else {
            // ---- fallback: rewrite every group (overwrites optimistic zeros), key compare ----
            #pragma unroll
            for (int j = 0; j < NCHUNK; ++j) {
                float4 o;
                o.x = (encf(v[j].x) >= T) ? v[j].x : 0.f;
                o.y = (encf(v[j].y) >= T) ? v[j].y : 0.f;
                o.z = (encf(v[j].z) >= T) ? v[j].z : 0.f;
                o.w = (encf(v[j].w) >= T) ? v[j].w : 0.f;
                orow[tid + j * TPB] = o;
            }
        }
    } else {
        // ---- rare stable tie path: keep first krem equals in column order; rewrites all groups ----
        unsigned* scan_arr = hist;               // reuse (2064 >= TPB words)
        unsigned run = 0;
        for (int j = 0; j < NCHUNK; ++j) {
            unsigned k0 = encf(v[j].x), k1 = encf(v[j].y), k2 = encf(v[j].z), k3 = encf(v[j].w);
            unsigned e0 = (k0 == T), e1 = (k1 == T), e2 = (k2 == T), e3 = (k3 == T);
            unsigned le = e0 + e1 + e2 + e3;
            __syncthreads();
            scan_arr[tid] = le;
            __syncthreads();
            for (int s = 1; s < TPB; s <<= 1) {
                unsigned t = (tid >= s) ? scan_arr[tid - s] : 0u;
                __syncthreads();
                scan_arr[tid] += t;
                __syncthreads();
            }
            unsigned excl = scan_arr[tid] - le;
            unsigned total = scan_arr[TPB - 1];
            unsigned r0 = run + excl;
            unsigned r1 = r0 + e0, r2 = r1 + e1, r3 = r2 + e2;
            float4 o;
            o.x = (k0 > T || (e0 && r0 < krem)) ? v[j].x : 0.f;
            o.y = (k1 > T || (e1 && r1 < krem)) ? v[j].y : 0.f;
            o.z = (k2 > T || (e2 && r2 < krem)) ? v[j].z : 0.f;
            o.w = (k3 > T || (e3 && r3 < krem)) ? v[j].w : 0.f;
            orow[tid + j * TPB] = o;
            run += total;
        }
    }
}

extern "C" void kernel_launch(void* const* d_in, const int* in_sizes, int n_in,
                              void* d_out, int out_size, void* d_ws, size_t ws_size,
                              hipStream_t stream) {
    const float* x = (const float*)d_in[0];
    float* out = (float*)d_out;
    const int B = in_sizes[0] / NCOL;   // 4096 rows
    topk_act_kernel<<<B, TPB, 0, stream>>>(x, out);
}

// Round 9
// 138.495 us; speedup vs baseline: 1.2361x; 1.2361x over previous
//
#include <hip/hip_runtime.h>

#define KTOP 100
#define NCOL 16384
#define TPB  1024
#define NCHUNK 4                 // 4 uint4 (16 values) per thread per row, in registers
#define RPB  8                   // rows per block (grid = 4096/8 = 512 -> 2 blocks/CU)
#define HST  520                 // per-copy stride: 512 bins + 8 pad (copies 8 banks apart)
#define HBUF (2*HST)             // one rotating buffer = 2 wave-group copies
#define CAP  1024                // candidate list capacity
#define BIN0 1536u               // (enc(2.0f) >> 21)
#define T0K  0xC0000000u         // enc(+2.0f)

// order-preserving key transform: a<b (float) <=> enc(a)<enc(b) (uint)
__device__ __forceinline__ unsigned enc(unsigned u){ return u ^ (((unsigned)((int)u>>31)) | 0x80000000u); }
__device__ __forceinline__ unsigned dec(unsigned k){ return k ^ ((k & 0x80000000u) ? 0x80000000u : 0xFFFFFFFFu); }

__global__ __launch_bounds__(TPB, 8)
void topk_act_kernel(const float* __restrict__ x, float* __restrict__ out, int nrow_total) {
    __shared__ unsigned h[3*HBUF];       // 3 rotating dual-copy 512-bin histograms (12.5 KB)
    __shared__ unsigned cand[CAP];       // 4 KB boundary-bin candidates
    __shared__ unsigned spos[3];
    __shared__ unsigned s_cnt, s_T, s_krem, s_eqc;

    const int tid = threadIdx.x, lane = tid & 63, wv = tid >> 6;
    const int row0 = blockIdx.x * RPB;
    int nrows = nrow_total - row0; if (nrows > RPB) nrows = RPB;
    if (nrows <= 0) return;

    for (int i = tid; i < 3*HBUF; i += TPB) h[i] = 0;
    if (tid < 3) spos[tid] = 0;
    if (tid == 0) s_cnt = 0;
    __syncthreads();

    uint4 v[NCHUNK];
    // ---- prologue: load row 0 -> regs, hist (keys >= 2.0) into buffer 0 ----
    {
        const uint4* xr = (const uint4*)(x + (size_t)row0 * NCOL);
        unsigned* hb = h + (wv & 1) * HST;
        unsigned pc = 0;
        #pragma unroll
        for (int j = 0; j < NCHUNK; ++j) {
            uint4 w = xr[tid + j*TPB];
            uint4 k; k.x=enc(w.x); k.y=enc(w.y); k.z=enc(w.z); k.w=enc(w.w);
            v[j] = k;
            if (k.x >= T0K){ atomicAdd(&hb[(k.x>>21)-BIN0],1u); ++pc; }
            if (k.y >= T0K){ atomicAdd(&hb[(k.y>>21)-BIN0],1u); ++pc; }
            if (k.z >= T0K){ atomicAdd(&hb[(k.z>>21)-BIN0],1u); ++pc; }
            if (k.w >= T0K){ atomicAdd(&hb[(k.w>>21)-BIN0],1u); ++pc; }
        }
        #pragma unroll
        for (int s=1;s<64;s<<=1) pc += __shfl_down(pc, s);
        if (lane==0) atomicAdd(&spos[0], pc);
    }
    __syncthreads();

    for (int r = 0; r < nrows; ++r) {
        const int cb = r % 3, nb = (r+1) % 3, zb = (r+2) % 3;
        uint4* orow = (uint4*)(out + (size_t)(row0 + r) * NCOL);
        const uint4* xnext = (const uint4*)(x + (size_t)(row0 + r + 1) * NCOL);
        const bool have_next = (r + 1 < nrows);

        // ---- S1: pass-0 boundary (hist of row r was filled before last barrier) ----
        unsigned pref, kcur, eqc; int sh;
        if (spos[cb] >= KTOP) {
            const unsigned* hb = h + cb*HBUF;           // dual-copy 512-bin scan; lane owns 8
            unsigned own = 0;
            #pragma unroll
            for (int w = 0; w < 8; ++w) own += hb[8*lane+w] + hb[HST + 8*lane+w];
            unsigned incl = own;
            #pragma unroll
            for (int s=1;s<64;s<<=1){ unsigned t=__shfl_down(incl,s); if (lane+s<64) incl+=t; }
            unsigned above = incl - own;
            bool hit = (above < KTOP) && (above + own >= KTOP);
            unsigned long long bal = __ballot(hit);
            int L = __ffsll((long long)bal) - 1;
            unsigned run = __shfl(above, L);
            unsigned sbin=0, sk=1, se=1;
            for (int w=7; w>=0; --w) {
                unsigned c = hb[8*L+w] + hb[HST + 8*L+w];
                unsigned rr = run + c;
                if (run < KTOP && rr >= KTOP){ sbin = 8u*L + (unsigned)w; sk = KTOP-run; se = c; }
                run = rr;
            }
            pref = (sbin + BIN0) << 21; kcur = sk; eqc = se; sh = 21;
        } else {
            // FALLBACK-A (data not N(0,1)-like): coarse 9-bit full-range hist in dead buffer h[zb]
            unsigned* hb = h + zb*HBUF;
            for (int i = tid; i < 512; i += TPB) hb[i] = 0;
            __syncthreads();
            #pragma unroll
            for (int j = 0; j < NCHUNK; ++j) {
                atomicAdd(&hb[v[j].x>>23],1u); atomicAdd(&hb[v[j].y>>23],1u);
                atomicAdd(&hb[v[j].z>>23],1u); atomicAdd(&hb[v[j].w>>23],1u);
            }
            __syncthreads();
            unsigned own = 0;
            #pragma unroll
            for (int w = 0; w < 8; ++w) own += hb[8*lane+w];
            unsigned incl = own;
            #pragma unroll
            for (int s=1;s<64;s<<=1){ unsigned t=__shfl_down(incl,s); if (lane+s<64) incl+=t; }
            unsigned above = incl - own;
            bool hit = (above < KTOP) && (above + own >= KTOP);
            unsigned long long bal = __ballot(hit);
            int L = __ffsll((long long)bal) - 1;
            unsigned run = __shfl(above, L);
            unsigned sbin=0, sk=1, se=1;
            for (int w=7; w>=0; --w) {
                unsigned c = hb[8*L+w];
                unsigned rr = run + c;
                if (run < KTOP && rr >= KTOP){ sbin = 8u*L + (unsigned)w; sk = KTOP-run; se = c; }
                run = rr;
            }
            pref = sbin << 23; kcur = sk; eqc = se; sh = 23;
            __syncthreads();                            // h[zb] reads done before reuse
        }

        bool done = (kcur == eqc);                      // T = bin floor, keep whole bin

        // ---- S2: exact T via candidate extraction + all-pairs rank (2 barriers) ----
        if (!done) {
            const unsigned pbin = pref >> sh;
            #pragma unroll
            for (int j = 0; j < NCHUNK; ++j) {
                if ((v[j].x >> sh) == pbin){ unsigned i=atomicAdd(&s_cnt,1u); if (i<CAP) cand[i]=v[j].x; }
                if ((v[j].y >> sh) == pbin){ unsigned i=atomicAdd(&s_cnt,1u); if (i<CAP) cand[i]=v[j].y; }
                if ((v[j].z >> sh) == pbin){ unsigned i=atomicAdd(&s_cnt,1u); if (i<CAP) cand[i]=v[j].z; }
                if ((v[j].w >> sh) == pbin){ unsigned i=atomicAdd(&s_cnt,1u); if (i<CAP) cand[i]=v[j].w; }
            }
            __syncthreads();
            const unsigned mtot = s_cnt;
            if (mtot <= CAP) {
                if (tid < (int)mtot) {                  // candidate tid: count greater/equal
                    unsigned c = cand[tid]; unsigned g=0,q=0;
                    for (unsigned j = 0; j < mtot; ++j) { unsigned cj = cand[j]; g += (cj > c); q += (cj == c); }
                    if (g < kcur && g + q >= kcur) { s_T = c; s_krem = kcur - g; s_eqc = q; }
                }
                __syncthreads();
                pref = s_T; kcur = s_krem; eqc = s_eqc;
            } else {
                // FALLBACK-B: generic multipass 7-bit refine from registers, hist in h[zb]
                int rb = sh; bool fdone = false;
                while (!fdone && rb > 0) {
                    const int step = rb >= 7 ? 7 : rb;
                    rb -= step;
                    const unsigned msk = (1u << step) - 1u;
                    const unsigned hib = (unsigned)(rb + step);
                    unsigned* hb = h + zb*HBUF;
                    __syncthreads();
                    for (int i = tid; i < 128; i += TPB) hb[i] = 0;
                    __syncthreads();
                    #pragma unroll
                    for (int j = 0; j < NCHUNK; ++j) {
                        if (((v[j].x ^ pref) >> hib) == 0) atomicAdd(&hb[(v[j].x >> rb) & msk], 1u);
                        if (((v[j].y ^ pref) >> hib) == 0) atomicAdd(&hb[(v[j].y >> rb) & msk], 1u);
                        if (((v[j].z ^ pref) >> hib) == 0) atomicAdd(&hb[(v[j].z >> rb) & msk], 1u);
                        if (((v[j].w ^ pref) >> hib) == 0) atomicAdd(&hb[(v[j].w >> rb) & msk], 1u);
                    }
                    __syncthreads();
                    unsigned t0 = hb[2*lane], t1 = hb[2*lane+1];
                    unsigned own = t0 + t1, incl = own;
                    #pragma unroll
                    for (int s=1;s<64;s<<=1){ unsigned t=__shfl_down(incl,s); if (lane+s<64) incl+=t; }
                    unsigned above = incl - own;
                    unsigned C1 = above + t1, C0 = C1 + t0;
                    bool h1 = (above < kcur) && (C1 >= kcur);
                    bool h0 = (C1 < kcur) && (C0 >= kcur);
                    unsigned mybin = h1 ? (2u*lane+1u) : (2u*lane);
                    unsigned myk   = h1 ? (kcur - above) : (kcur - C1);
                    unsigned mye   = h1 ? t1 : t0;
                    unsigned long long bal = __ballot(h0 || h1);
                    int L = __ffsll((long long)bal) - 1;
                    pref |= __shfl(mybin, L) << rb;
                    kcur  = __shfl(myk, L);
                    eqc   = __shfl(mye, L);
                    fdone = (kcur == eqc);
                }
                __syncthreads();                        // h[zb] reads done
            }
        }

        const unsigned T = pref;
        const unsigned krem = kcur;
        const bool tie = (krem < eqc);

        if (!tie) {
            // ---- S3: zero next-next buffer; S4: fused store(row r) + load(row r+1) ----
            for (int i = tid; i < HBUF; i += TPB) h[zb*HBUF + i] = 0;
            if (tid == 0) { spos[zb] = 0; s_cnt = 0; }
            unsigned* hn = h + nb*HBUF + (wv&1)*HST;
            unsigned pc = 0;
            #pragma unroll
            for (int j = 0; j < NCHUNK; ++j) {
                uint4 k = v[j];
                uint4 o;
                o.x = (k.x >= T) ? dec(k.x) : 0u;
                o.y = (k.y >= T) ? dec(k.y) : 0u;
                o.z = (k.z >= T) ? dec(k.z) : 0u;
                o.w = (k.w >= T) ? dec(k.w) : 0u;
                orow[tid + j*TPB] = o;                  // dense full-line store
                if (have_next) {                        // interleaved next-row load
                    uint4 w = xnext[tid + j*TPB];
                    uint4 k2; k2.x=enc(w.x); k2.y=enc(w.y); k2.z=enc(w.z); k2.w=enc(w.w);
                    v[j] = k2;
                    if (k2.x >= T0K){ atomicAdd(&hn[(k2.x>>21)-BIN0],1u); ++pc; }
                    if (k2.y >= T0K){ atomicAdd(&hn[(k2.y>>21)-BIN0],1u); ++pc; }
                    if (k2.z >= T0K){ atomicAdd(&hn[(k2.z>>21)-BIN0],1u); ++pc; }
                    if (k2.w >= T0K){ atomicAdd(&hn[(k2.w>>21)-BIN0],1u); ++pc; }
                }
            }
            if (have_next) {
                #pragma unroll
                for (int s=1;s<64;s<<=1) pc += __shfl_down(pc, s);
                if (lane==0) atomicAdd(&spos[nb], pc);
            }
        } else {
            // ---- rare stable tie path: keep first krem equals in column order ----
            unsigned* scan_arr = h + zb*HBUF;           // dead buffer as scan space
            unsigned run = 0;
            for (int j = 0; j < NCHUNK; ++j) {
                uint4 k = v[j];
                unsigned e0=(k.x==T), e1=(k.y==T), e2=(k.z==T), e3=(k.w==T);
                unsigned le = e0+e1+e2+e3;
                __syncthreads();
                scan_arr[tid] = le;
                __syncthreads();
                for (int s=1;s<TPB;s<<=1){
                    unsigned t = (tid>=s)?scan_arr[tid-s]:0u;
                    __syncthreads();
                    scan_arr[tid] += t;
                    __syncthreads();
                }
                unsigned excl = scan_arr[tid]-le;
                unsigned total = scan_arr[TPB-1];
                unsigned r0 = run+excl, r1=r0+e0, r2=r1+e1, r3=r2+e2;
                uint4 o;
                o.x = (k.x>T || (e0 && r0<krem)) ? dec(k.x) : 0u;
                o.y = (k.y>T || (e1 && r1<krem)) ? dec(k.y) : 0u;
                o.z = (k.z>T || (e2 && r2<krem)) ? dec(k.z) : 0u;
                o.w = (k.w>T || (e3 && r3<krem)) ? dec(k.w) : 0u;
                orow[tid + j*TPB] = o;
                run += total;
            }
            __syncthreads();
            for (int i = tid; i < HBUF; i += TPB) h[zb*HBUF + i] = 0;
            if (tid == 0) { spos[zb] = 0; s_cnt = 0; }
            if (have_next) {
                unsigned* hn = h + nb*HBUF + (wv&1)*HST;
                unsigned pc = 0;
                #pragma unroll
                for (int j = 0; j < NCHUNK; ++j) {
                    uint4 w = xnext[tid + j*TPB];
                    uint4 k2; k2.x=enc(w.x); k2.y=enc(w.y); k2.z=enc(w.z); k2.w=enc(w.w);
                    v[j] = k2;
                    if (k2.x >= T0K){ atomicAdd(&hn[(k2.x>>21)-BIN0],1u); ++pc; }
                    if (k2.y >= T0K){ atomicAdd(&hn[(k2.y>>21)-BIN0],1u); ++pc; }
                    if (k2.z >= T0K){ atomicAdd(&hn[(k2.z>>21)-BIN0],1u); ++pc; }
                    if (k2.w >= T0K){ atomicAdd(&hn[(k2.w>>21)-BIN0],1u); ++pc; }
                }
                #pragma unroll
                for (int s=1;s<64;s<<=1) pc += __shfl_down(pc, s);
                if (lane==0) atomicAdd(&spos[nb], pc);
            }
        }
        __syncthreads();   // END: h[nb] complete, h[zb] zeroed -> next iteration
    }
}

extern "C" void kernel_launch(void* const* d_in, const int* in_sizes, int n_in,
                              void* d_out, int out_size, void* d_ws, size_t ws_size,
                              hipStream_t stream) {
    const float* x = (const float*)d_in[0];
    float* out = (float*)d_out;
    const int B = in_sizes[0] / NCOL;   // 4096 rows
    const int grid = (B + RPB - 1) / RPB;
    topk_act_kernel<<<grid, TPB, 0, stream>>>(x, out, B);
}